// Round 5
// baseline (476.636 us; speedup 1.0000x reference)
//
#include <hip/hip_runtime.h>
#include <hip/hip_bf16.h>
#include <stdint.h>

typedef short bf16x8 __attribute__((ext_vector_type(8)));
typedef float f32x4 __attribute__((ext_vector_type(4)));
typedef float f32x16 __attribute__((ext_vector_type(16)));
typedef unsigned int u32x2 __attribute__((ext_vector_type(2)));
typedef unsigned int u32x4 __attribute__((ext_vector_type(4)));

__device__ __forceinline__ unsigned short f2bf(float f) {
  union { float f; unsigned u; } x; x.f = f;
  unsigned r = x.u + 0x7FFFu + ((x.u >> 16) & 1u);
  return (unsigned short)(r >> 16);
}

__device__ __forceinline__ unsigned pk2bf(float a, float b) {
  union { __hip_bfloat162 h; unsigned u; } x;
  x.h = __float22bfloat162_rn(make_float2(a, b));
  return x.u;
}

typedef const __attribute__((address_space(1))) unsigned int* gptr_t;
typedef __attribute__((address_space(3))) unsigned int* lptr_t;
__device__ __forceinline__ void gll16(const void* g, void* l) {
  __builtin_amdgcn_global_load_lds((gptr_t)g, (lptr_t)l, 16, 0, 0);
}

#define EXPC 0.18033688011112042f  // 0.125 * log2(e)

// ---------------- W transpose: [K=1024][N=1024] fp32 -> [N][K] bf16 ----------
// z==0 (Wq) additionally scaled by EXPC so attn can use exp2 directly.
__global__ __launch_bounds__(1024) void wt_kernel(const float* __restrict__ Wq,
                                                  const float* __restrict__ Wk,
                                                  const float* __restrict__ Wv,
                                                  unsigned short* __restrict__ wt) {
  const float* W = blockIdx.z == 0 ? Wq : (blockIdx.z == 1 ? Wk : Wv);
  float sc = blockIdx.z == 0 ? EXPC : 1.0f;
  unsigned short* o = wt + (size_t)blockIdx.z * 1048576;
  __shared__ float t[32][33];
  int tx = threadIdx.x, ty = threadIdx.y;
  t[ty][tx] = W[(size_t)(blockIdx.y * 32 + ty) * 1024 + blockIdx.x * 32 + tx] * sc;
  __syncthreads();
  o[(size_t)(blockIdx.x * 32 + ty) * 1024 + blockIdx.y * 32 + tx] = f2bf(t[tx][ty]);
}

// ---------------- X fp32 -> bf16 (Q,K,V concatenated) ------------------------
__global__ __launch_bounds__(256) void cvt_kernel(const float* __restrict__ Q,
                                                  const float* __restrict__ K,
                                                  const float* __restrict__ V,
                                                  unsigned short* __restrict__ out) {
  int y = blockIdx.y;
  const float* s = y == 0 ? Q : (y == 1 ? K : V);
  unsigned short* o = out + (size_t)y * 8388608;
  size_t idx = ((size_t)blockIdx.x * 256 + threadIdx.x) * 8;
  float4 f0 = *(const float4*)(s + idx);
  float4 f1 = *(const float4*)(s + idx + 4);
  u32x4 r = {pk2bf(f0.x, f0.y), pk2bf(f0.z, f0.w), pk2bf(f1.x, f1.y), pk2bf(f1.z, f1.w)};
  *(u32x4*)(o + idx) = r;
}

// ---------------- projection GEMM: C[8192,1024] = Xb @ W^T + b ---------------
// 1D grid, XCD-swizzled so each XCD's blocks share an X stripe + W (L2 reuse).
// isv epilogue premultiplies V rows by mask (numerator fold).
__global__ __launch_bounds__(256) void proj_kernel(
    const unsigned short* __restrict__ Xb, const unsigned short* __restrict__ wt,
    const float* __restrict__ bq, const float* __restrict__ bk, const float* __restrict__ bv,
    const float* __restrict__ mask,
    unsigned short* __restrict__ qo, unsigned short* __restrict__ ko, unsigned short* __restrict__ vo) {
  // decode: xcd = bid&7 handles m-stripe [xcd*8, xcd*8+8) for all n, all p
  int bid = blockIdx.x;
  int xcd = bid & 7;
  int j6 = bid >> 3;          // 0..191
  int p = j6 >> 6;            // 0..2
  int jj = j6 & 63;
  int nloc = jj & 7;          // n fast -> X stripe stays resident
  int mloc = jj >> 3;
  int m0 = (xcd * 8 + mloc) * 128, n0 = nloc * 128;

  const unsigned short* X = Xb + (size_t)p * 8388608;
  const unsigned short* Wt = wt + (size_t)p * 1048576;
  const float* bias = p == 0 ? bq : (p == 1 ? bk : bv);
  unsigned short* out = p == 0 ? qo : (p == 1 ? ko : vo);
  float bscale = (p == 0) ? EXPC : 1.0f;

  __shared__ __align__(16) unsigned short smem[16384];  // 32KB
  unsigned short* abuf = smem;
  unsigned short* bbuf = smem + 8192;

  int tid = threadIdx.x;
  int lane = tid & 63, w = tid >> 6;
  int l15 = lane & 15, quad = lane >> 4;
  int wm = w >> 1, wn = w & 1;

  f32x4 acc[4][4] = {};

  for (int kk = 0; kk < 16; ++kk) {
    int k0 = kk * 64;
    for (int j = 0; j < 4; ++j) {
      int stj = w * 4 + j;
      int kt = stj >> 3, t = stj & 7;
      gll16(Wt + (size_t)(n0 + t * 16 + l15) * 1024 + k0 + kt * 32 + quad * 8, &bbuf[stj * 512]);
      gll16(X + (size_t)(m0 + t * 16 + l15) * 1024 + k0 + kt * 32 + quad * 8, &abuf[stj * 512]);
    }
    __syncthreads();
    for (int kt = 0; kt < 2; ++kt) {
      bf16x8 af[4], bfr[4];
      for (int i = 0; i < 4; ++i) af[i]  = *(const bf16x8*)&abuf[(kt * 8 + wm * 4 + i) * 512 + lane * 8];
      for (int j = 0; j < 4; ++j) bfr[j] = *(const bf16x8*)&bbuf[(kt * 8 + wn * 4 + j) * 512 + lane * 8];
      for (int i = 0; i < 4; ++i)
        for (int j = 0; j < 4; ++j)
          acc[i][j] = __builtin_amdgcn_mfma_f32_16x16x32_bf16(af[i], bfr[j], acc[i][j], 0, 0, 0);
    }
    __syncthreads();
  }

  // ---- epilogue via LDS [lead 64][payload 128] stride 136, 2 passes ----
  bool isv = (p == 2);
  int b = m0 >> 11;
  float bl[4];
  for (int j = 0; j < 4; ++j) bl[j] = bias[n0 + wn * 64 + j * 16 + l15] * bscale;

  __syncthreads();
  for (int p2 = 0; p2 < 2; ++p2) {
    if (!isv) {
      if (wm == p2) {
        for (int i = 0; i < 4; ++i)
          for (int j = 0; j < 4; ++j) {
            int col = wn * 64 + j * 16 + l15;
            for (int r = 0; r < 4; ++r) {
              int row = i * 16 + quad * 4 + r;
              smem[row * 136 + col] = f2bf(acc[i][j][r] + bl[j]);
            }
          }
      }
    } else {
      if (wn == p2) {
        for (int j = 0; j < 4; ++j) {
          int row = j * 16 + l15;
          for (int i = 0; i < 4; ++i) {
            int colm = wm * 64 + i * 16 + quad * 4;
            float4 mv = *(const float4*)&mask[(size_t)b * 2048 + (m0 & 2047) + colm];
            unsigned u0 = pk2bf((acc[i][j][0] + bl[j]) * mv.x, (acc[i][j][1] + bl[j]) * mv.y);
            unsigned u1 = pk2bf((acc[i][j][2] + bl[j]) * mv.z, (acc[i][j][3] + bl[j]) * mv.w);
            *(unsigned*)&smem[row * 136 + colm] = u0;
            *(unsigned*)&smem[row * 136 + colm + 2] = u1;
          }
        }
      }
    }
    __syncthreads();
    for (int t = 0; t < 4; ++t) {
      int chunk = t * 256 + tid;
      int row = chunk >> 4, cseg = chunk & 15;
      u32x4 v = *(const u32x4*)&smem[row * 136 + cseg * 8];
      size_t idx;
      if (!isv) {
        int m = m0 + p2 * 64 + row;
        int s = m & 2047;
        int n = n0 + cseg * 8;
        int hh = n >> 6, d = n & 63;
        idx = ((size_t)((b * 16 + hh) * 2048 + s) << 6) + d;
      } else {
        int n = n0 + p2 * 64 + row;
        int hh = n >> 6, d = n & 63;
        int s = (m0 & 2047) + cseg * 8;
        idx = ((size_t)((b * 16 + hh) * 64 + d) << 11) + s;
      }
      *(u32x4*)(out + idx) = v;
    }
    __syncthreads();
  }
}

// ---------------- fused attention (32x32x16 MFMA) ---------------------------
// 1D grid XCD-swizzled: one XCD hosts 8 heads (K,V = 4MB = L2).
// Q pre-scaled (exp2 direct), V pre-masked, den via mask-A MFMA.
__global__ __launch_bounds__(256) void attn_kernel(
    const unsigned short* __restrict__ q, const unsigned short* __restrict__ k,
    const unsigned short* __restrict__ vT, const float* __restrict__ mask,
    float* __restrict__ out) {
  int bid = blockIdx.x;
  int hl = (bid & 7) | ((bid >> 7) << 3);  // head-linear 0..63, const per XCD set
  int qb = (bid >> 3) & 15;
  int b = hl >> 4, hh = hl & 15;

  int tid = threadIdx.x, lane = tid & 63, w = tid >> 6;
  int c = lane & 31, hf = lane >> 5;

  __shared__ __align__(16) unsigned short smem[18432];  // 36KB: K 16 + V 16 + mask 4
  unsigned short* kls = smem;
  unsigned short* vls = smem + 8192;
  unsigned short* mls = smem + 16384;

  const unsigned short* qp = q + (size_t)(b * 16 + hh) * 2048 * 64;
  const unsigned short* kp = k + (size_t)(b * 16 + hh) * 2048 * 64;
  const unsigned short* vp = vT + (size_t)(b * 16 + hh) * 64 * 2048;
  const float* mp = mask + (size_t)b * 2048;

  // stage mask row as bf16 into LDS (first loop barrier makes it visible)
  {
    float4 a0 = *(const float4*)(mp + tid * 8);
    float4 a1 = *(const float4*)(mp + tid * 8 + 4);
    u32x4 r = {pk2bf(a0.x, a0.y), pk2bf(a0.z, a0.w), pk2bf(a1.x, a1.y), pk2bf(a1.z, a1.w)};
    *(u32x4*)&mls[tid * 8] = r;
  }

  int q0 = qb * 128 + w * 32;
  bf16x8 qf[4];
  for (int sl = 0; sl < 4; ++sl)
    qf[sl] = *(const bf16x8*)(qp + (size_t)(q0 + c) * 64 + sl * 16 + hf * 8);

  f32x16 oacc[2] = {};  // O^T: col=qrow, row=dv-local
  f32x16 dacc = {};     // den: all rows equal, col=qrow
  int paddr = (lane ^ 32) << 2;

  for (int kb = 0; kb < 16; ++kb) {
    int kbase = kb * 128;
    __syncthreads();
    for (int j = 0; j < 8; ++j) {
      int st = w * 8 + j;
      if (st < 16) {
        int mt = st >> 2, sl = st & 3;
        gll16(kp + (size_t)(kbase + mt * 32 + c) * 64 + sl * 16 + hf * 8, &kls[st * 512]);
      } else {
        int sv = st - 16;
        int dvt = sv >> 3, ks = sv & 7;
        gll16(vp + (size_t)(dvt * 32 + c) * 2048 + kbase + ks * 16 + hf * 8, &vls[sv * 512]);
      }
    }
    __syncthreads();

    for (int mt = 0; mt < 4; ++mt) {
      // S^T 32x32 tile (Q pre-scaled: e = exp2(sc))
      f32x16 sc = {};
      for (int sl = 0; sl < 4; ++sl) {
        bf16x8 ak = *(const bf16x8*)&kls[(mt * 4 + sl) * 512 + lane * 8];
        sc = __builtin_amdgcn_mfma_f32_32x32x16_bf16(ak, qf[sl], sc, 0, 0, 0);
      }
      unsigned pk[8];
      for (int g = 0; g < 4; ++g) {
        float e0 = exp2f(sc[4 * g + 0]);
        float e1 = exp2f(sc[4 * g + 1]);
        float e2 = exp2f(sc[4 * g + 2]);
        float e3 = exp2f(sc[4 * g + 3]);
        pk[2 * g] = pk2bf(e0, e1);
        pk[2 * g + 1] = pk2bf(e2, e3);
      }
      for (int s = 0; s < 2; ++s) {
        unsigned ta = hf ? pk[4 * s + 0] : pk[4 * s + 2];
        unsigned tb = hf ? pk[4 * s + 1] : pk[4 * s + 3];
        unsigned ba = (unsigned)__builtin_amdgcn_ds_bpermute(paddr, (int)ta);
        unsigned bb = (unsigned)__builtin_amdgcn_ds_bpermute(paddr, (int)tb);
        union { unsigned u[4]; bf16x8 v; } pf;
        pf.u[0] = hf ? ba : pk[4 * s + 0];
        pf.u[1] = hf ? bb : pk[4 * s + 1];
        pf.u[2] = hf ? pk[4 * s + 2] : ba;
        pf.u[3] = hf ? pk[4 * s + 3] : bb;
        // den: A = mask row (broadcast across m), B = P^T
        bf16x8 mf = *(const bf16x8*)&mls[kbase + mt * 32 + s * 16 + hf * 8];
        dacc = __builtin_amdgcn_mfma_f32_32x32x16_bf16(mf, pf.v, dacc, 0, 0, 0);
        int ks = mt * 2 + s;
        for (int dvt = 0; dvt < 2; ++dvt) {
          bf16x8 av = *(const bf16x8*)&vls[(dvt * 8 + ks) * 512 + lane * 8];
          oacc[dvt] = __builtin_amdgcn_mfma_f32_32x32x16_bf16(av, pf.v, oacc[dvt], 0, 0, 0);
        }
      }
    }
  }

  float rden = 1.0f / (dacc[0] + 1e-8f);

  // epilogue: O^T -> O via per-wave LDS transpose (2 passes of 16 qrows)
  __syncthreads();
  float* ew = (float*)smem + w * 2048;  // 8KB per wave
  for (int cp = 0; cp < 2; ++cp) {
    if ((c >> 4) == cp) {
      for (int dvt = 0; dvt < 2; ++dvt)
        for (int r = 0; r < 16; r += 2) {
          int dv = dvt * 32 + (r & 3) + 8 * (r >> 2) + 4 * hf;
          float2 val = make_float2(oacc[dvt][r] * rden, oacc[dvt][r + 1] * rden);
          *(float2*)&ew[(c & 15) * 68 + dv] = val;
        }
    }
    __syncthreads();
    int row = lane >> 2, seg = lane & 3;
    int s = q0 + cp * 16 + row;
    float* op = out + (size_t)(b * 2048 + s) * 1024 + hh * 64 + seg * 16;
    const float* src = &ew[row * 68 + seg * 16];
    for (int i = 0; i < 4; ++i)
      *(float4*)(op + i * 4) = *(const float4*)(src + i * 4);
    __syncthreads();
  }
}

extern "C" void kernel_launch(void* const* d_in, const int* in_sizes, int n_in,
                              void* d_out, int out_size, void* d_ws, size_t ws_size,
                              hipStream_t stream) {
  const float* Q    = (const float*)d_in[0];
  const float* K    = (const float*)d_in[1];
  const float* V    = (const float*)d_in[2];
  const float* mask = (const float*)d_in[3];
  const float* Wq   = (const float*)d_in[4];
  const float* bq   = (const float*)d_in[5];
  const float* Wk   = (const float*)d_in[6];
  const float* bk   = (const float*)d_in[7];
  const float* Wv   = (const float*)d_in[8];
  const float* bv   = (const float*)d_in[9];

  char* ws = (char*)d_ws;
  unsigned short* wt = (unsigned short*)ws;                  // 6MB: 3 x bf16 W^T
  unsigned short* qb = (unsigned short*)(ws + 6291456);      // 16MB [B,H,S,64]
  unsigned short* kb = (unsigned short*)(ws + 23068672);     // 16MB [B,H,S,64]
  unsigned short* vb = (unsigned short*)(ws + 39845888);     // 16MB [B,H,64,S] (pre-masked)
  unsigned short* xb = (unsigned short*)(ws + 56623104);     // 48MB bf16 Q,K,V

  hipLaunchKernelGGL(wt_kernel, dim3(32, 32, 3), dim3(32, 32), 0, stream, Wq, Wk, Wv, wt);
  hipLaunchKernelGGL(cvt_kernel, dim3(4096, 3), dim3(256), 0, stream, Q, K, V, xb);
  hipLaunchKernelGGL(proj_kernel, dim3(1536), dim3(256), 0, stream,
                     xb, wt, bq, bk, bv, mask, qb, kb, vb);
  hipLaunchKernelGGL(attn_kernel, dim3(1024), dim3(256), 0, stream,
                     qb, kb, vb, mask, (float*)d_out);
}

// Round 6
// 475.952 us; speedup vs baseline: 1.0014x; 1.0014x over previous
//
#include <hip/hip_runtime.h>
#include <hip/hip_bf16.h>
#include <stdint.h>

typedef short bf16x8 __attribute__((ext_vector_type(8)));
typedef float f32x4 __attribute__((ext_vector_type(4)));
typedef float f32x16 __attribute__((ext_vector_type(16)));
typedef unsigned int u32x2 __attribute__((ext_vector_type(2)));
typedef unsigned int u32x4 __attribute__((ext_vector_type(4)));

__device__ __forceinline__ unsigned short f2bf(float f) {
  union { float f; unsigned u; } x; x.f = f;
  unsigned r = x.u + 0x7FFFu + ((x.u >> 16) & 1u);
  return (unsigned short)(r >> 16);
}

__device__ __forceinline__ unsigned pk2bf(float a, float b) {
  union { __hip_bfloat162 h; unsigned u; } x;
  x.h = __float22bfloat162_rn(make_float2(a, b));
  return x.u;
}

typedef const __attribute__((address_space(1))) unsigned int* gptr_t;
typedef __attribute__((address_space(3))) unsigned int* lptr_t;
__device__ __forceinline__ void gll16(const void* g, void* l) {
  __builtin_amdgcn_global_load_lds((gptr_t)g, (lptr_t)l, 16, 0, 0);
}

#define EXPC 0.18033688011112042f  // 0.125 * log2(e)

// ---------------- W transpose: [K=1024][N=1024] fp32 -> [N][K] bf16 ----------
__global__ __launch_bounds__(1024) void wt_kernel(const float* __restrict__ Wq,
                                                  const float* __restrict__ Wk,
                                                  const float* __restrict__ Wv,
                                                  unsigned short* __restrict__ wt) {
  const float* W = blockIdx.z == 0 ? Wq : (blockIdx.z == 1 ? Wk : Wv);
  float sc = blockIdx.z == 0 ? EXPC : 1.0f;
  unsigned short* o = wt + (size_t)blockIdx.z * 1048576;
  __shared__ float t[32][33];
  int tx = threadIdx.x, ty = threadIdx.y;
  t[ty][tx] = W[(size_t)(blockIdx.y * 32 + ty) * 1024 + blockIdx.x * 32 + tx] * sc;
  __syncthreads();
  o[(size_t)(blockIdx.x * 32 + ty) * 1024 + blockIdx.y * 32 + tx] = f2bf(t[tx][ty]);
}

// ---------------- X fp32 -> bf16 (Q,K,V concatenated) ------------------------
__global__ __launch_bounds__(256) void cvt_kernel(const float* __restrict__ Q,
                                                  const float* __restrict__ K,
                                                  const float* __restrict__ V,
                                                  unsigned short* __restrict__ out) {
  int y = blockIdx.y;
  const float* s = y == 0 ? Q : (y == 1 ? K : V);
  unsigned short* o = out + (size_t)y * 8388608;
  size_t idx = ((size_t)blockIdx.x * 256 + threadIdx.x) * 8;
  float4 f0 = *(const float4*)(s + idx);
  float4 f1 = *(const float4*)(s + idx + 4);
  u32x4 r = {pk2bf(f0.x, f0.y), pk2bf(f0.z, f0.w), pk2bf(f1.x, f1.y), pk2bf(f1.z, f1.w)};
  *(u32x4*)(o + idx) = r;
}

// ---------------- projection GEMM: C[8192,1024] = Xb @ W^T + b ---------------
// BK=32 (occupancy: single frag set live -> target VGPR<=128, 4 blocks/CU).
// XCD-swizzled 1D grid; isv epilogue premultiplies V rows by mask.
__global__ __launch_bounds__(256) void proj_kernel(
    const unsigned short* __restrict__ Xb, const unsigned short* __restrict__ wt,
    const float* __restrict__ bq, const float* __restrict__ bk, const float* __restrict__ bv,
    const float* __restrict__ mask,
    unsigned short* __restrict__ qo, unsigned short* __restrict__ ko, unsigned short* __restrict__ vo) {
  int bid = blockIdx.x;
  int xcd = bid & 7;
  int j6 = bid >> 3;          // 0..191
  int p = j6 >> 6;            // 0..2
  int jj = j6 & 63;
  int nloc = jj & 7;          // n fast -> X stripe resident in this XCD's L2
  int mloc = jj >> 3;
  int m0 = (xcd * 8 + mloc) * 128, n0 = nloc * 128;

  const unsigned short* X = Xb + (size_t)p * 8388608;
  const unsigned short* Wt = wt + (size_t)p * 1048576;
  const float* bias = p == 0 ? bq : (p == 1 ? bk : bv);
  unsigned short* out = p == 0 ? qo : (p == 1 ? ko : vo);
  float bscale = (p == 0) ? EXPC : 1.0f;

  __shared__ __align__(16) unsigned short smem[8704];  // 17KB (stage 16K, epi 17K)
  unsigned short* bbuf = smem;         // 8KB: B tile 128x32
  unsigned short* abuf = smem + 4096;  // 8KB: A tile 128x32

  int tid = threadIdx.x;
  int lane = tid & 63, w = tid >> 6;
  int l15 = lane & 15, quad = lane >> 4;
  int wm = w >> 1, wn = w & 1;

  f32x4 acc[4][4] = {};

  for (int kk = 0; kk < 32; ++kk) {
    int k0 = kk * 32;
    // 4 gll16 per wave; waves 0-1 stage B subtiles 0-7, waves 2-3 stage A 0-7
    for (int j = 0; j < 4; ++j) {
      int stj = w * 4 + j;
      if (stj < 8)
        gll16(Wt + (size_t)(n0 + stj * 16 + l15) * 1024 + k0 + quad * 8, &bbuf[stj * 512]);
      else
        gll16(X + (size_t)(m0 + (stj - 8) * 16 + l15) * 1024 + k0 + quad * 8, &abuf[(stj - 8) * 512]);
    }
    __syncthreads();
    bf16x8 af[4], bfr[4];
    for (int i = 0; i < 4; ++i) af[i]  = *(const bf16x8*)&abuf[(wm * 4 + i) * 512 + lane * 8];
    for (int j = 0; j < 4; ++j) bfr[j] = *(const bf16x8*)&bbuf[(wn * 4 + j) * 512 + lane * 8];
    for (int i = 0; i < 4; ++i)
      for (int j = 0; j < 4; ++j)
        acc[i][j] = __builtin_amdgcn_mfma_f32_16x16x32_bf16(af[i], bfr[j], acc[i][j], 0, 0, 0);
    __syncthreads();
  }

  // ---- epilogue via LDS [lead 64][payload 128] stride 136, 2 passes ----
  bool isv = (p == 2);
  int b = m0 >> 11;
  float bl[4];
  for (int j = 0; j < 4; ++j) bl[j] = bias[n0 + wn * 64 + j * 16 + l15] * bscale;

  __syncthreads();
  for (int p2 = 0; p2 < 2; ++p2) {
    if (!isv) {
      if (wm == p2) {
        for (int i = 0; i < 4; ++i)
          for (int j = 0; j < 4; ++j) {
            int col = wn * 64 + j * 16 + l15;
            for (int r = 0; r < 4; ++r) {
              int row = i * 16 + quad * 4 + r;
              smem[row * 136 + col] = f2bf(acc[i][j][r] + bl[j]);
            }
          }
      }
    } else {
      if (wn == p2) {
        for (int j = 0; j < 4; ++j) {
          int row = j * 16 + l15;
          for (int i = 0; i < 4; ++i) {
            int colm = wm * 64 + i * 16 + quad * 4;
            float4 mv = *(const float4*)&mask[(size_t)b * 2048 + (m0 & 2047) + colm];
            unsigned u0 = pk2bf((acc[i][j][0] + bl[j]) * mv.x, (acc[i][j][1] + bl[j]) * mv.y);
            unsigned u1 = pk2bf((acc[i][j][2] + bl[j]) * mv.z, (acc[i][j][3] + bl[j]) * mv.w);
            *(unsigned*)&smem[row * 136 + colm] = u0;
            *(unsigned*)&smem[row * 136 + colm + 2] = u1;
          }
        }
      }
    }
    __syncthreads();
    for (int t = 0; t < 4; ++t) {
      int chunk = t * 256 + tid;
      int row = chunk >> 4, cseg = chunk & 15;
      u32x4 v = *(const u32x4*)&smem[row * 136 + cseg * 8];
      size_t idx;
      if (!isv) {
        int m = m0 + p2 * 64 + row;
        int s = m & 2047;
        int n = n0 + cseg * 8;
        int hh = n >> 6, d = n & 63;
        idx = ((size_t)((b * 16 + hh) * 2048 + s) << 6) + d;
      } else {
        int n = n0 + p2 * 64 + row;
        int hh = n >> 6, d = n & 63;
        int s = (m0 & 2047) + cseg * 8;
        idx = ((size_t)((b * 16 + hh) * 64 + d) << 11) + s;
      }
      *(u32x4*)(out + idx) = v;
    }
    __syncthreads();
  }
}

// ---------------- fused attention (32x32x16 MFMA) ---------------------------
// 1D grid XCD-swizzled: one XCD hosts 8 heads (K,V = 4MB = L2).
// Q pre-scaled (exp2 direct), V pre-masked, den via mask-A MFMA.
__global__ __launch_bounds__(256) void attn_kernel(
    const unsigned short* __restrict__ q, const unsigned short* __restrict__ k,
    const unsigned short* __restrict__ vT, const float* __restrict__ mask,
    float* __restrict__ out) {
  int bid = blockIdx.x;
  int hl = (bid & 7) | ((bid >> 7) << 3);  // head-linear 0..63, const per XCD set
  int qb = (bid >> 3) & 15;
  int b = hl >> 4, hh = hl & 15;

  int tid = threadIdx.x, lane = tid & 63, w = tid >> 6;
  int c = lane & 31, hf = lane >> 5;

  __shared__ __align__(16) unsigned short smem[18432];  // 36KB: K 16 + V 16 + mask 4
  unsigned short* kls = smem;
  unsigned short* vls = smem + 8192;
  unsigned short* mls = smem + 16384;

  const unsigned short* qp = q + (size_t)(b * 16 + hh) * 2048 * 64;
  const unsigned short* kp = k + (size_t)(b * 16 + hh) * 2048 * 64;
  const unsigned short* vp = vT + (size_t)(b * 16 + hh) * 64 * 2048;
  const float* mp = mask + (size_t)b * 2048;

  {
    float4 a0 = *(const float4*)(mp + tid * 8);
    float4 a1 = *(const float4*)(mp + tid * 8 + 4);
    u32x4 r = {pk2bf(a0.x, a0.y), pk2bf(a0.z, a0.w), pk2bf(a1.x, a1.y), pk2bf(a1.z, a1.w)};
    *(u32x4*)&mls[tid * 8] = r;
  }

  int q0 = qb * 128 + w * 32;
  bf16x8 qf[4];
  for (int sl = 0; sl < 4; ++sl)
    qf[sl] = *(const bf16x8*)(qp + (size_t)(q0 + c) * 64 + sl * 16 + hf * 8);

  f32x16 oacc[2] = {};  // O^T: col=qrow, row=dv-local
  f32x16 dacc = {};     // den: all rows equal, col=qrow
  int paddr = (lane ^ 32) << 2;

  for (int kb = 0; kb < 16; ++kb) {
    int kbase = kb * 128;
    __syncthreads();
    for (int j = 0; j < 8; ++j) {
      int st = w * 8 + j;
      if (st < 16) {
        int mt = st >> 2, sl = st & 3;
        gll16(kp + (size_t)(kbase + mt * 32 + c) * 64 + sl * 16 + hf * 8, &kls[st * 512]);
      } else {
        int sv = st - 16;
        int dvt = sv >> 3, ks = sv & 7;
        gll16(vp + (size_t)(dvt * 32 + c) * 2048 + kbase + ks * 16 + hf * 8, &vls[sv * 512]);
      }
    }
    __syncthreads();

    for (int mt = 0; mt < 4; ++mt) {
      f32x16 sc = {};
      for (int sl = 0; sl < 4; ++sl) {
        bf16x8 ak = *(const bf16x8*)&kls[(mt * 4 + sl) * 512 + lane * 8];
        sc = __builtin_amdgcn_mfma_f32_32x32x16_bf16(ak, qf[sl], sc, 0, 0, 0);
      }
      unsigned pk[8];
      for (int g = 0; g < 4; ++g) {
        float e0 = exp2f(sc[4 * g + 0]);
        float e1 = exp2f(sc[4 * g + 1]);
        float e2 = exp2f(sc[4 * g + 2]);
        float e3 = exp2f(sc[4 * g + 3]);
        pk[2 * g] = pk2bf(e0, e1);
        pk[2 * g + 1] = pk2bf(e2, e3);
      }
      for (int s = 0; s < 2; ++s) {
        unsigned ta = hf ? pk[4 * s + 0] : pk[4 * s + 2];
        unsigned tb = hf ? pk[4 * s + 1] : pk[4 * s + 3];
        unsigned ba = (unsigned)__builtin_amdgcn_ds_bpermute(paddr, (int)ta);
        unsigned bb = (unsigned)__builtin_amdgcn_ds_bpermute(paddr, (int)tb);
        union { unsigned u[4]; bf16x8 v; } pf;
        pf.u[0] = hf ? ba : pk[4 * s + 0];
        pf.u[1] = hf ? bb : pk[4 * s + 1];
        pf.u[2] = hf ? pk[4 * s + 2] : ba;
        pf.u[3] = hf ? pk[4 * s + 3] : bb;
        bf16x8 mf = *(const bf16x8*)&mls[kbase + mt * 32 + s * 16 + hf * 8];
        dacc = __builtin_amdgcn_mfma_f32_32x32x16_bf16(mf, pf.v, dacc, 0, 0, 0);
        int ks = mt * 2 + s;
        for (int dvt = 0; dvt < 2; ++dvt) {
          bf16x8 av = *(const bf16x8*)&vls[(dvt * 8 + ks) * 512 + lane * 8];
          oacc[dvt] = __builtin_amdgcn_mfma_f32_32x32x16_bf16(av, pf.v, oacc[dvt], 0, 0, 0);
        }
      }
    }
  }

  float rden = 1.0f / (dacc[0] + 1e-8f);

  __syncthreads();
  float* ew = (float*)smem + w * 2048;  // 8KB per wave
  for (int cp = 0; cp < 2; ++cp) {
    if ((c >> 4) == cp) {
      for (int dvt = 0; dvt < 2; ++dvt)
        for (int r = 0; r < 16; r += 2) {
          int dv = dvt * 32 + (r & 3) + 8 * (r >> 2) + 4 * hf;
          float2 val = make_float2(oacc[dvt][r] * rden, oacc[dvt][r + 1] * rden);
          *(float2*)&ew[(c & 15) * 68 + dv] = val;
        }
    }
    __syncthreads();
    int row = lane >> 2, seg = lane & 3;
    int s = q0 + cp * 16 + row;
    float* op = out + (size_t)(b * 2048 + s) * 1024 + hh * 64 + seg * 16;
    const float* src = &ew[row * 68 + seg * 16];
    for (int i = 0; i < 4; ++i)
      *(float4*)(op + i * 4) = *(const float4*)(src + i * 4);
    __syncthreads();
  }
}

extern "C" void kernel_launch(void* const* d_in, const int* in_sizes, int n_in,
                              void* d_out, int out_size, void* d_ws, size_t ws_size,
                              hipStream_t stream) {
  const float* Q    = (const float*)d_in[0];
  const float* K    = (const float*)d_in[1];
  const float* V    = (const float*)d_in[2];
  const float* mask = (const float*)d_in[3];
  const float* Wq   = (const float*)d_in[4];
  const float* bq   = (const float*)d_in[5];
  const float* Wk   = (const float*)d_in[6];
  const float* bk   = (const float*)d_in[7];
  const float* Wv   = (const float*)d_in[8];
  const float* bv   = (const float*)d_in[9];

  char* ws = (char*)d_ws;
  unsigned short* wt = (unsigned short*)ws;                  // 6MB: 3 x bf16 W^T
  unsigned short* qb = (unsigned short*)(ws + 6291456);      // 16MB [B,H,S,64]
  unsigned short* kb = (unsigned short*)(ws + 23068672);     // 16MB [B,H,S,64]
  unsigned short* vb = (unsigned short*)(ws + 39845888);     // 16MB [B,H,64,S] (pre-masked)
  unsigned short* xb = (unsigned short*)(ws + 56623104);     // 48MB bf16 Q,K,V

  hipLaunchKernelGGL(wt_kernel, dim3(32, 32, 3), dim3(32, 32), 0, stream, Wq, Wk, Wv, wt);
  hipLaunchKernelGGL(cvt_kernel, dim3(4096, 3), dim3(256), 0, stream, Q, K, V, xb);
  hipLaunchKernelGGL(proj_kernel, dim3(1536), dim3(256), 0, stream,
                     xb, wt, bq, bk, bv, mask, qb, kb, vb);
  hipLaunchKernelGGL(attn_kernel, dim3(1024), dim3(256), 0, stream,
                     qb, kb, vb, mask, (float*)d_out);
}